// Round 1
// baseline (700.964 us; speedup 1.0000x reference)
//
#include <hip/hip_runtime.h>
#include <math.h>

#define NPOS 2304   // 48*48
#define CC   256    // DIM
#define DI   512    // HEADS*DIM_HEAD
#define HH   8
#define DHH  64
#define NT   36     // NPOS/64
#define SCALE 0.125f
#define MASKV -100.0f

// ---------------- Kernel 1: ChannelRMSNorm ----------------
// normed[b][c][j] = fmap / max(||fmap[:,j]||, eps) * 16 * gamma[c]
__global__ __launch_bounds__(256) void k_rmsnorm(const float* __restrict__ fmap,
                                                 const float* __restrict__ gamma,
                                                 float* __restrict__ normed) {
    const int b  = blockIdx.y;
    const int j0 = blockIdx.x * 64;
    const int tx = threadIdx.x & 63;
    const int ty = threadIdx.x >> 6;
    __shared__ float red[4][64];
    __shared__ float inv[64];
    __shared__ float gs[256];
    gs[threadIdx.x] = gamma[threadIdx.x];
    const float* fb = fmap + (size_t)b * CC * NPOS;
    float s = 0.0f;
#pragma unroll 8
    for (int i = 0; i < 64; ++i) {
        const int c = ty + 4 * i;
        const float v = fb[c * NPOS + j0 + tx];
        s += v * v;
    }
    red[ty][tx] = s;
    __syncthreads();
    if (threadIdx.x < 64) {
        const float t = red[0][tx] + red[1][tx] + red[2][tx] + red[3][tx];
        inv[tx] = 16.0f / fmaxf(sqrtf(t), 1e-12f);
    }
    __syncthreads();
    float* nb = normed + (size_t)b * CC * NPOS;
#pragma unroll 8
    for (int i = 0; i < 64; ++i) {
        const int c = ty + 4 * i;
        nb[c * NPOS + j0 + tx] = fb[c * NPOS + j0 + tx] * inv[tx] * gs[c];
    }
}

// ---------------- Kernel 2: fused qk/v projection GEMM ----------------
// O[o][j] = sum_c Wcat[o][c] * normed[b][c][j], o in [0,1024); o<512 -> w_qk->qk, else w_v->v
// Output layout: (b, o, j) with j contiguous.
__global__ __launch_bounds__(256) void k_proj(const float* __restrict__ normed,
                                              const float* __restrict__ w_qk,
                                              const float* __restrict__ w_v,
                                              float* __restrict__ qk,
                                              float* __restrict__ v) {
    const int b  = blockIdx.z;
    const int o0 = blockIdx.y * 64;   // 0..1023
    const int j0 = blockIdx.x * 64;
    const int t  = threadIdx.x;
    const int trow = t >> 4, tcol = t & 15;
    __shared__ float Ast[16][68];   // Ast[k][o]
    __shared__ float Bs[16][68];    // Bs[k][j]
    float acc[4][4] = {};
    const float* W = (o0 < 512) ? w_qk : w_v;
    const int or0 = (o0 < 512) ? o0 : (o0 - 512);
    const float* nb = normed + (size_t)b * CC * NPOS;
    for (int k0 = 0; k0 < 256; k0 += 16) {
        {   // A tile: 64 rows x 16 k, transpose into Ast[k][o]
            const int o = t >> 2, kq = t & 3;
            const float4 w4 = *(const float4*)&W[(or0 + o) * 256 + k0 + kq * 4];
            Ast[kq * 4 + 0][o] = w4.x; Ast[kq * 4 + 1][o] = w4.y;
            Ast[kq * 4 + 2][o] = w4.z; Ast[kq * 4 + 3][o] = w4.w;
        }
        {   // B tile: 16 k rows x 64 j (row-contiguous)
            const int kk = t >> 4, jq = t & 15;
            const float4 b4 = *(const float4*)&nb[(k0 + kk) * NPOS + j0 + jq * 4];
            *(float4*)&Bs[kk][jq * 4] = b4;
        }
        __syncthreads();
#pragma unroll
        for (int kk = 0; kk < 16; ++kk) {
            const float4 a4 = *(const float4*)&Ast[kk][trow * 4];
            const float4 b4 = *(const float4*)&Bs[kk][tcol * 4];
            const float a[4]  = {a4.x, a4.y, a4.z, a4.w};
            const float bb[4] = {b4.x, b4.y, b4.z, b4.w};
#pragma unroll
            for (int i = 0; i < 4; ++i)
#pragma unroll
                for (int j = 0; j < 4; ++j)
                    acc[i][j] += a[i] * bb[j];
        }
        __syncthreads();
    }
    float* dst = ((o0 < 512) ? qk : v) + (size_t)b * DI * NPOS;
#pragma unroll
    for (int i = 0; i < 4; ++i) {
        const int o = or0 + trow * 4 + i;
        const float4 r = make_float4(acc[i][0], acc[i][1], acc[i][2], acc[i][3]);
        *(float4*)&dst[(size_t)o * NPOS + j0 + tcol * 4] = r;
    }
}

// ---------------- Kernel 3: flash-style L2-distance attention ----------------
// Per (b,h) and 64-query tile. sim = -sqrt(max(q2+k2-2*q.k,0))*scale, self-masked;
// null key/value as softmax prologue. Output inner[b][j][h*64+d].
__global__ __launch_bounds__(256) void k_attn(const float* __restrict__ qk,
                                              const float* __restrict__ v,
                                              const float* __restrict__ null_kv,
                                              float* __restrict__ inner) {
    const int qt = blockIdx.x, bh = blockIdx.y;
    const int b = bh >> 3, h = bh & 7;
    const int t  = threadIdx.x;
    const int tx = t & 63, ty = t >> 6;
    const int trow = t >> 4, tcol = t & 15;
    __shared__ float Qt[64][68];   // Qt[d][q]
    __shared__ float KV[64][68];   // phase A: Kt[d][k]; phase B: Vs[k][d]
    __shared__ float Pt[64][68];   // Pt[k][q]: scores -> probs (transposed)
    __shared__ float q2s[64], k2s[64], ms[64], ls[64], arow[64];
    __shared__ float part[4][64];
    __shared__ float nks[64], nvs[64];

    const float* qbase = qk + ((size_t)b * DI + h * 64) * NPOS;  // row d, stride NPOS
    const float* vbase = v  + ((size_t)b * DI + h * 64) * NPOS;
    const int j0 = qt * 64;

    // Q tile (transposed load: global row d is j-contiguous)
#pragma unroll
    for (int r = 0; r < 16; ++r) {
        const int d = r * 4 + ty;
        Qt[d][tx] = qbase[d * NPOS + j0 + tx];
    }
    if (t < 64) { nks[t] = null_kv[h * 64 + t]; nvs[t] = null_kv[512 + h * 64 + t]; }
    __syncthreads();
    {   // q2
        float s = 0.0f;
#pragma unroll
        for (int i = 0; i < 16; ++i) { const float q = Qt[ty * 16 + i][tx]; s += q * q; }
        part[ty][tx] = s;
    }
    __syncthreads();
    if (t < 64) {
        const float q2 = part[0][t] + part[1][t] + part[2][t] + part[3][t];
        q2s[t] = q2;
        float nk2 = 0.0f, dot = 0.0f;
        for (int d = 0; d < 64; ++d) {
            const float kd = nks[d];
            nk2 += kd * kd;
            dot += Qt[d][t] * kd;
        }
        const float d2 = fmaxf(q2 + nk2 - 2.0f * dot, 0.0f);
        ms[t] = -sqrtf(d2) * SCALE;   // running max init = null sim
        ls[t] = 1.0f;                 // exp(null - m) = 1
    }
    __syncthreads();
    float oacc[4][4];
#pragma unroll
    for (int i = 0; i < 4; ++i)
#pragma unroll
        for (int j = 0; j < 4; ++j) oacc[i][j] = nvs[tcol * 4 + j];  // O = 1 * null_v

    for (int kt = 0; kt < NT; ++kt) {
        const int kj0 = kt * 64;
        __syncthreads();   // prev PV reads of KV/Pt done
        // K tile -> KV[d][k]
#pragma unroll
        for (int r = 0; r < 16; ++r) {
            const int d = r * 4 + ty;
            KV[d][tx] = qbase[d * NPOS + kj0 + tx];
        }
        __syncthreads();
        {   // k2
            float s = 0.0f;
#pragma unroll
            for (int i = 0; i < 16; ++i) { const float kk = KV[ty * 16 + i][tx]; s += kk * kk; }
            part[ty][tx] = s;
        }
        __syncthreads();
        if (t < 64) k2s[t] = part[0][t] + part[1][t] + part[2][t] + part[3][t];
        __syncthreads();
        // scores: 4x4 register tile
        float sc[4][4] = {};
#pragma unroll 8
        for (int d = 0; d < 64; ++d) {
            const float4 a4 = *(const float4*)&Qt[d][trow * 4];
            const float4 b4 = *(const float4*)&KV[d][tcol * 4];
            const float a[4]  = {a4.x, a4.y, a4.z, a4.w};
            const float bb[4] = {b4.x, b4.y, b4.z, b4.w};
#pragma unroll
            for (int i = 0; i < 4; ++i)
#pragma unroll
                for (int j = 0; j < 4; ++j)
                    sc[i][j] += a[i] * bb[j];
        }
        // to sim + self-mask, store transposed Pt[k][q]
#pragma unroll
        for (int j = 0; j < 4; ++j) {
            const int gk = kj0 + tcol * 4 + j;
            float col[4];
#pragma unroll
            for (int i = 0; i < 4; ++i) {
                const int gq = j0 + trow * 4 + i;
                const float d2 = fmaxf(q2s[trow * 4 + i] + k2s[tcol * 4 + j] - 2.0f * sc[i][j], 0.0f);
                const float sim = -sqrtf(d2) * SCALE;
                col[i] = (gq == gk) ? MASKV : sim;
            }
            *(float4*)&Pt[tcol * 4 + j][trow * 4] = make_float4(col[0], col[1], col[2], col[3]);
        }
        __syncthreads();
        {   // tile row-max (4 segments of 16 keys per row)
            const int q = t & 63, seg = t >> 6;
            float mx = -1e30f;
#pragma unroll
            for (int i = 0; i < 16; ++i) mx = fmaxf(mx, Pt[seg * 16 + i][q]);
            part[seg][q] = mx;
        }
        __syncthreads();
        if (t < 64) {
            const float tm = fmaxf(fmaxf(part[0][t], part[1][t]), fmaxf(part[2][t], part[3][t]));
            const float mold = ms[t];
            const float mnew = fmaxf(mold, tm);
            ms[t] = mnew;
            arow[t] = expf(mold - mnew);
        }
        __syncthreads();
        {   // exponentiate + partial row sums
            const int q = t & 63, seg = t >> 6;
            const float mnew = ms[q];
            float s = 0.0f;
#pragma unroll
            for (int i = 0; i < 16; ++i) {
                const float p = expf(Pt[seg * 16 + i][q] - mnew);
                Pt[seg * 16 + i][q] = p;
                s += p;
            }
            part[seg][q] = s;
        }
        __syncthreads();
        if (t < 64)
            ls[t] = ls[t] * arow[t] + part[0][t] + part[1][t] + part[2][t] + part[3][t];
        {   // rescale O accumulators
            float al[4];
#pragma unroll
            for (int i = 0; i < 4; ++i) al[i] = arow[trow * 4 + i];
#pragma unroll
            for (int i = 0; i < 4; ++i)
#pragma unroll
                for (int j = 0; j < 4; ++j) oacc[i][j] *= al[i];
        }
        __syncthreads();
        // V tile -> KV[k][d] (transposed store)
#pragma unroll
        for (int r = 0; r < 16; ++r) {
            const int d = r * 4 + ty;
            KV[tx][d] = vbase[d * NPOS + kj0 + tx];
        }
        __syncthreads();
        // PV: O[q][d] += sum_k P[q][k] * V[k][d]
#pragma unroll 8
        for (int kk = 0; kk < 64; ++kk) {
            const float4 p4 = *(const float4*)&Pt[kk][trow * 4];
            const float4 v4 = *(const float4*)&KV[kk][tcol * 4];
            const float p[4]  = {p4.x, p4.y, p4.z, p4.w};
            const float vv[4] = {v4.x, v4.y, v4.z, v4.w};
#pragma unroll
            for (int i = 0; i < 4; ++i)
#pragma unroll
                for (int j = 0; j < 4; ++j)
                    oacc[i][j] += p[i] * vv[j];
        }
    }
    // epilogue: divide by l, write inner[b][q][h*64+d]
    float il[4];
#pragma unroll
    for (int i = 0; i < 4; ++i) il[i] = 1.0f / ls[trow * 4 + i];
    float* ob = inner + (size_t)b * NPOS * DI;
#pragma unroll
    for (int i = 0; i < 4; ++i) {
        const int q = j0 + trow * 4 + i;
        const float4 r = make_float4(oacc[i][0] * il[i], oacc[i][1] * il[i],
                                     oacc[i][2] * il[i], oacc[i][3] * il[i]);
        *(float4*)&ob[(size_t)q * DI + h * 64 + tcol * 4] = r;
    }
}

// ---------------- Kernel 4: output projection ----------------
// out[b][c][j] = sum_o w_out[c][o] * inner[b][j][o]
__global__ __launch_bounds__(256) void k_out(const float* __restrict__ w_out,
                                             const float* __restrict__ inner,
                                             float* __restrict__ out) {
    const int b  = blockIdx.z;
    const int c0 = blockIdx.y * 64;
    const int j0 = blockIdx.x * 64;
    const int t  = threadIdx.x;
    const int trow = t >> 4, tcol = t & 15;
    __shared__ float Ast[16][68];  // Ast[k][c]
    __shared__ float Bst[16][68];  // Bst[k][j]
    float acc[4][4] = {};
    const float* ib = inner + (size_t)b * NPOS * DI;
    for (int k0 = 0; k0 < 512; k0 += 16) {
        {   // A: w_out rows c0..c0+63, k-contiguous -> transpose
            const int cr = t >> 2, kq = t & 3;
            const float4 w4 = *(const float4*)&w_out[(c0 + cr) * DI + k0 + kq * 4];
            Ast[kq * 4 + 0][cr] = w4.x; Ast[kq * 4 + 1][cr] = w4.y;
            Ast[kq * 4 + 2][cr] = w4.z; Ast[kq * 4 + 3][cr] = w4.w;
        }
        {   // B: inner rows j0..j0+63, k-contiguous -> transpose
            const int jr = t >> 2, kq = t & 3;
            const float4 i4 = *(const float4*)&ib[(size_t)(j0 + jr) * DI + k0 + kq * 4];
            Bst[kq * 4 + 0][jr] = i4.x; Bst[kq * 4 + 1][jr] = i4.y;
            Bst[kq * 4 + 2][jr] = i4.z; Bst[kq * 4 + 3][jr] = i4.w;
        }
        __syncthreads();
#pragma unroll
        for (int kk = 0; kk < 16; ++kk) {
            const float4 a4 = *(const float4*)&Ast[kk][trow * 4];
            const float4 b4 = *(const float4*)&Bst[kk][tcol * 4];
            const float a[4]  = {a4.x, a4.y, a4.z, a4.w};
            const float bb[4] = {b4.x, b4.y, b4.z, b4.w};
#pragma unroll
            for (int i = 0; i < 4; ++i)
#pragma unroll
                for (int j = 0; j < 4; ++j)
                    acc[i][j] += a[i] * bb[j];
        }
        __syncthreads();
    }
    float* ob = out + (size_t)b * CC * NPOS;
#pragma unroll
    for (int i = 0; i < 4; ++i) {
        const float4 r = make_float4(acc[i][0], acc[i][1], acc[i][2], acc[i][3]);
        *(float4*)&ob[(size_t)(c0 + trow * 4 + i) * NPOS + j0 + tcol * 4] = r;
    }
}

extern "C" void kernel_launch(void* const* d_in, const int* in_sizes, int n_in,
                              void* d_out, int out_size, void* d_ws, size_t ws_size,
                              hipStream_t stream) {
    const float* fmap    = (const float*)d_in[0];
    const float* gamma   = (const float*)d_in[1];
    const float* w_qk    = (const float*)d_in[2];
    const float* w_v     = (const float*)d_in[3];
    const float* null_kv = (const float*)d_in[4];
    const float* w_out   = (const float*)d_in[5];
    float* out = (float*)d_out;
    float* ws  = (float*)d_ws;
    float* normed = ws;                       // 2*256*2304   = 1,179,648
    float* qkb    = normed + 1179648;         // 2*512*2304   = 2,359,296
    float* vb     = qkb    + 2359296;
    float* inner  = vb     + 2359296;         // 2*2304*512   = 2,359,296
    // total 8,257,536 floats = 33.0 MB of workspace

    hipLaunchKernelGGL(k_rmsnorm, dim3(NT, 2),     dim3(256), 0, stream, fmap, gamma, normed);
    hipLaunchKernelGGL(k_proj,    dim3(NT, 16, 2), dim3(256), 0, stream, normed, w_qk, w_v, qkb, vb);
    hipLaunchKernelGGL(k_attn,    dim3(NT, 16),    dim3(256), 0, stream, qkb, vb, null_kv, inner);
    hipLaunchKernelGGL(k_out,     dim3(NT, 4, 2),  dim3(256), 0, stream, w_out, inner, out);
}

// Round 2
// 628.841 us; speedup vs baseline: 1.1147x; 1.1147x over previous
//
#include <hip/hip_runtime.h>
#include <math.h>

#define NPOS 2304   // 48*48
#define CC   256    // DIM
#define DI   512    // HEADS*DIM_HEAD
#define NT   36     // NPOS/64
#define SCALE 0.125f
#define MASKV -100.0f

// ---------------- Kernel 1: ChannelRMSNorm ----------------
__global__ __launch_bounds__(256) void k_rmsnorm(const float* __restrict__ fmap,
                                                 const float* __restrict__ gamma,
                                                 float* __restrict__ normed) {
    const int b  = blockIdx.y;
    const int j0 = blockIdx.x * 64;
    const int tx = threadIdx.x & 63;
    const int ty = threadIdx.x >> 6;
    __shared__ float red[4][64];
    __shared__ float inv[64];
    __shared__ float gs[256];
    gs[threadIdx.x] = gamma[threadIdx.x];
    const float* fb = fmap + (size_t)b * CC * NPOS;
    float s = 0.0f;
#pragma unroll 8
    for (int i = 0; i < 64; ++i) {
        const int c = ty + 4 * i;
        const float v = fb[c * NPOS + j0 + tx];
        s += v * v;
    }
    red[ty][tx] = s;
    __syncthreads();
    if (threadIdx.x < 64) {
        const float t = red[0][tx] + red[1][tx] + red[2][tx] + red[3][tx];
        inv[tx] = 16.0f / fmaxf(sqrtf(t), 1e-12f);
    }
    __syncthreads();
    float* nb = normed + (size_t)b * CC * NPOS;
#pragma unroll 8
    for (int i = 0; i < 64; ++i) {
        const int c = ty + 4 * i;
        nb[c * NPOS + j0 + tx] = fb[c * NPOS + j0 + tx] * inv[tx] * gs[c];
    }
}

// ---------------- Kernel 2: fused qk/v projection GEMM + sq epilogue ----------------
// O[o][j] = sum_c Wcat[o][c] * normed[b][c][j]; o<512 -> qk (+ per-head sq), else v.
__global__ __launch_bounds__(256) void k_proj(const float* __restrict__ normed,
                                              const float* __restrict__ w_qk,
                                              const float* __restrict__ w_v,
                                              float* __restrict__ qk,
                                              float* __restrict__ v,
                                              float* __restrict__ sq) {
    const int b  = blockIdx.z;
    const int o0 = blockIdx.y * 64;   // 0..1023
    const int j0 = blockIdx.x * 64;
    const int t  = threadIdx.x;
    const int trow = t >> 4, tcol = t & 15;
    __shared__ float Ast[16][68];   // Ast[k][o]
    __shared__ float Bs[16][68];    // Bs[k][j]
    float acc[4][4] = {};
    const float* W = (o0 < DI) ? w_qk : w_v;
    const int or0 = (o0 < DI) ? o0 : (o0 - DI);
    const float* nb = normed + (size_t)b * CC * NPOS;
    for (int k0 = 0; k0 < 256; k0 += 16) {
        {   // A tile: 64 rows x 16 k, transpose into Ast[k][o]
            const int o = t >> 2, kq = t & 3;
            const float4 w4 = *(const float4*)&W[(or0 + o) * 256 + k0 + kq * 4];
            Ast[kq * 4 + 0][o] = w4.x; Ast[kq * 4 + 1][o] = w4.y;
            Ast[kq * 4 + 2][o] = w4.z; Ast[kq * 4 + 3][o] = w4.w;
        }
        {   // B tile: 16 k rows x 64 j
            const int kk = t >> 4, jq = t & 15;
            const float4 b4 = *(const float4*)&nb[(k0 + kk) * NPOS + j0 + jq * 4];
            *(float4*)&Bs[kk][jq * 4] = b4;
        }
        __syncthreads();
#pragma unroll
        for (int kk = 0; kk < 16; ++kk) {
            const float4 a4 = *(const float4*)&Ast[kk][trow * 4];
            const float4 b4 = *(const float4*)&Bs[kk][tcol * 4];
            const float a[4]  = {a4.x, a4.y, a4.z, a4.w};
            const float bb[4] = {b4.x, b4.y, b4.z, b4.w};
#pragma unroll
            for (int i = 0; i < 4; ++i)
#pragma unroll
                for (int j = 0; j < 4; ++j)
                    acc[i][j] += a[i] * bb[j];
        }
        __syncthreads();
    }
    float* dst = ((o0 < DI) ? qk : v) + (size_t)b * DI * NPOS;
#pragma unroll
    for (int i = 0; i < 4; ++i) {
        const int o = or0 + trow * 4 + i;
        const float4 r = make_float4(acc[i][0], acc[i][1], acc[i][2], acc[i][3]);
        *(float4*)&dst[(size_t)o * NPOS + j0 + tcol * 4] = r;
    }
    if (o0 < DI) {
        // per-column sum of squares of this 64(o) x 64(j) tile == sq for head o0>>6
        float sjj[4];
#pragma unroll
        for (int jj = 0; jj < 4; ++jj) {
            float ts = 0.0f;
#pragma unroll
            for (int i = 0; i < 4; ++i) ts += acc[i][jj] * acc[i][jj];
            sjj[jj] = ts;
        }
        // loop above ended with __syncthreads(): Ast free to reuse
        *(float4*)&Ast[trow][tcol * 4] = make_float4(sjj[0], sjj[1], sjj[2], sjj[3]);
        __syncthreads();
        if (t < 64) {
            float tot = 0.0f;
#pragma unroll
            for (int r = 0; r < 16; ++r) tot += Ast[r][t];
            sq[((size_t)b * 8 + (o0 >> 6)) * NPOS + j0 + t] = tot;
        }
    }
}

// ---------------- Kernel 3: flash-style L2-distance attention ----------------
// Shuffle-softmax: m,l,alpha in registers replicated across the 16 lanes per trow.
__global__ __launch_bounds__(256, 3) void k_attn(const float* __restrict__ qk,
                                                 const float* __restrict__ v,
                                                 const float* __restrict__ null_kv,
                                                 const float* __restrict__ sq,
                                                 float* __restrict__ inner) {
    const int qt = blockIdx.x, bh = blockIdx.y;
    const int b = bh >> 3, h = bh & 7;
    const int t  = threadIdx.x;
    const int trow = t >> 4, tcol = t & 15;
    __shared__ float Qt[64][64];   // Qt[d][q]  (no pad: broadcast/stride-1 access only)
    __shared__ float KV[64][68];   // phase A: Kt[d][k]; phase B: Vs[k][d]
    __shared__ float Pt[64][68];   // Pt[k][q] probs (transposed)
    __shared__ float nks[64], nvs[64];

    const float* qbase = qk + ((size_t)b * DI + h * 64) * NPOS;
    const float* vbase = v  + ((size_t)b * DI + h * 64) * NPOS;
    const float* sqb   = sq + (size_t)bh * NPOS;
    const int j0 = qt * 64;

    // Q tile: float4 global loads, [d][q] LDS layout
#pragma unroll
    for (int r = 0; r < 4; ++r) {
        const int d = r * 16 + trow;
        const float4 q4 = *(const float4*)&qbase[d * NPOS + j0 + tcol * 4];
        *(float4*)&Qt[d][tcol * 4] = q4;
    }
    if (t < 64) { nks[t] = null_kv[h * 64 + t]; nvs[t] = null_kv[DI + h * 64 + t]; }
    __syncthreads();

    float q2v[4];
#pragma unroll
    for (int i = 0; i < 4; ++i) q2v[i] = sqb[j0 + trow * 4 + i];

    // null prologue: m0 = sim(q, null_k), l0 = 1, O0 = null_v
    float mreg[4], lreg[4], oacc[4][4];
    {
        float dot[4] = {}; float nk2 = 0.0f;
#pragma unroll 8
        for (int d = 0; d < 64; ++d) {
            const float nk = nks[d];
            nk2 += nk * nk;
#pragma unroll
            for (int i = 0; i < 4; ++i) dot[i] += Qt[d][trow * 4 + i] * nk;
        }
#pragma unroll
        for (int i = 0; i < 4; ++i) {
            const float d2 = fmaxf(q2v[i] + nk2 - 2.0f * dot[i], 0.0f);
            mreg[i] = -sqrtf(d2) * SCALE;
            lreg[i] = 1.0f;
        }
#pragma unroll
        for (int i = 0; i < 4; ++i)
#pragma unroll
            for (int j = 0; j < 4; ++j) oacc[i][j] = nvs[tcol * 4 + j];
    }

    for (int kt = 0; kt < NT; ++kt) {
        const int kj0 = kt * 64;
        __syncthreads();   // prev PV reads of KV/Pt done
        // K tile -> KV[d][k], float4 loads
#pragma unroll
        for (int r = 0; r < 4; ++r) {
            const int d = r * 16 + trow;
            const float4 k4 = *(const float4*)&qbase[d * NPOS + kj0 + tcol * 4];
            *(float4*)&KV[d][tcol * 4] = k4;
        }
        float k2v[4];
#pragma unroll
        for (int j = 0; j < 4; ++j) k2v[j] = sqb[kj0 + tcol * 4 + j];
        __syncthreads();

        // scores
        float sc[4][4] = {};
#pragma unroll 8
        for (int d = 0; d < 64; ++d) {
            const float4 a4 = *(const float4*)&Qt[d][trow * 4];
            const float4 b4 = *(const float4*)&KV[d][tcol * 4];
            const float a[4]  = {a4.x, a4.y, a4.z, a4.w};
            const float bb[4] = {b4.x, b4.y, b4.z, b4.w};
#pragma unroll
            for (int i = 0; i < 4; ++i)
#pragma unroll
                for (int j = 0; j < 4; ++j)
                    sc[i][j] += a[i] * bb[j];
        }

        // sim + self-mask + online softmax (register/shuffle)
        float p[4][4], tm[4];
#pragma unroll
        for (int i = 0; i < 4; ++i) tm[i] = -1e30f;
#pragma unroll
        for (int i = 0; i < 4; ++i) {
            const int gq = j0 + trow * 4 + i;
#pragma unroll
            for (int j = 0; j < 4; ++j) {
                const int gk = kj0 + tcol * 4 + j;
                const float d2 = fmaxf(q2v[i] + k2v[j] - 2.0f * sc[i][j], 0.0f);
                float s = -sqrtf(d2) * SCALE;
                if (gq == gk) s = MASKV;
                p[i][j] = s;                      // holds sim for now
                tm[i] = fmaxf(tm[i], s);
            }
        }
#pragma unroll
        for (int mk = 1; mk <= 8; mk <<= 1)
#pragma unroll
            for (int i = 0; i < 4; ++i) tm[i] = fmaxf(tm[i], __shfl_xor(tm[i], mk));
        float alpha[4], rs[4] = {};
#pragma unroll
        for (int i = 0; i < 4; ++i) {
            const float mnew = fmaxf(mreg[i], tm[i]);
            alpha[i] = __expf(mreg[i] - mnew);
            mreg[i] = mnew;
        }
#pragma unroll
        for (int i = 0; i < 4; ++i)
#pragma unroll
            for (int j = 0; j < 4; ++j) {
                const float e = __expf(p[i][j] - mreg[i]);
                p[i][j] = e;
                rs[i] += e;
            }
#pragma unroll
        for (int mk = 1; mk <= 8; mk <<= 1)
#pragma unroll
            for (int i = 0; i < 4; ++i) rs[i] += __shfl_xor(rs[i], mk);
#pragma unroll
        for (int i = 0; i < 4; ++i) lreg[i] = lreg[i] * alpha[i] + rs[i];
#pragma unroll
        for (int i = 0; i < 4; ++i)
#pragma unroll
            for (int j = 0; j < 4; ++j) oacc[i][j] *= alpha[i];

        // store P transposed: Pt[k][q]
#pragma unroll
        for (int j = 0; j < 4; ++j)
            *(float4*)&Pt[tcol * 4 + j][trow * 4] =
                make_float4(p[0][j], p[1][j], p[2][j], p[3][j]);
        __syncthreads();   // Pt visible; score reads of KV done

        // V tile -> KV[k][d] (transposed store; float4 global load)
#pragma unroll
        for (int r = 0; r < 4; ++r) {
            const int d = r * 16 + trow;
            const float4 v4 = *(const float4*)&vbase[d * NPOS + kj0 + tcol * 4];
            KV[tcol * 4 + 0][d] = v4.x;
            KV[tcol * 4 + 1][d] = v4.y;
            KV[tcol * 4 + 2][d] = v4.z;
            KV[tcol * 4 + 3][d] = v4.w;
        }
        __syncthreads();

        // PV: O[q][d] += P[q][k] * V[k][d]
#pragma unroll 8
        for (int kk = 0; kk < 64; ++kk) {
            const float4 p4 = *(const float4*)&Pt[kk][trow * 4];
            const float4 v4 = *(const float4*)&KV[kk][tcol * 4];
            const float pp[4] = {p4.x, p4.y, p4.z, p4.w};
            const float vv[4] = {v4.x, v4.y, v4.z, v4.w};
#pragma unroll
            for (int i = 0; i < 4; ++i)
#pragma unroll
                for (int j = 0; j < 4; ++j)
                    oacc[i][j] += pp[i] * vv[j];
        }
    }

    // epilogue
    float il[4];
#pragma unroll
    for (int i = 0; i < 4; ++i) il[i] = 1.0f / lreg[i];
    float* ob = inner + (size_t)b * NPOS * DI;
#pragma unroll
    for (int i = 0; i < 4; ++i) {
        const int q = j0 + trow * 4 + i;
        const float4 r = make_float4(oacc[i][0] * il[i], oacc[i][1] * il[i],
                                     oacc[i][2] * il[i], oacc[i][3] * il[i]);
        *(float4*)&ob[(size_t)q * DI + h * 64 + tcol * 4] = r;
    }
}

// ---------------- Kernel 4: output projection ----------------
__global__ __launch_bounds__(256) void k_out(const float* __restrict__ w_out,
                                             const float* __restrict__ inner,
                                             float* __restrict__ out) {
    const int b  = blockIdx.z;
    const int c0 = blockIdx.y * 64;
    const int j0 = blockIdx.x * 64;
    const int t  = threadIdx.x;
    const int trow = t >> 4, tcol = t & 15;
    __shared__ float Ast[16][68];  // Ast[k][c]
    __shared__ float Bst[16][68];  // Bst[k][j]
    float acc[4][4] = {};
    const float* ib = inner + (size_t)b * NPOS * DI;
    for (int k0 = 0; k0 < 512; k0 += 16) {
        {
            const int cr = t >> 2, kq = t & 3;
            const float4 w4 = *(const float4*)&w_out[(c0 + cr) * DI + k0 + kq * 4];
            Ast[kq * 4 + 0][cr] = w4.x; Ast[kq * 4 + 1][cr] = w4.y;
            Ast[kq * 4 + 2][cr] = w4.z; Ast[kq * 4 + 3][cr] = w4.w;
        }
        {
            const int jr = t >> 2, kq = t & 3;
            const float4 i4 = *(const float4*)&ib[(size_t)(j0 + jr) * DI + k0 + kq * 4];
            Bst[kq * 4 + 0][jr] = i4.x; Bst[kq * 4 + 1][jr] = i4.y;
            Bst[kq * 4 + 2][jr] = i4.z; Bst[kq * 4 + 3][jr] = i4.w;
        }
        __syncthreads();
#pragma unroll
        for (int kk = 0; kk < 16; ++kk) {
            const float4 a4 = *(const float4*)&Ast[kk][trow * 4];
            const float4 b4 = *(const float4*)&Bst[kk][tcol * 4];
            const float a[4]  = {a4.x, a4.y, a4.z, a4.w};
            const float bb[4] = {b4.x, b4.y, b4.z, b4.w};
#pragma unroll
            for (int i = 0; i < 4; ++i)
#pragma unroll
                for (int j = 0; j < 4; ++j)
                    acc[i][j] += a[i] * bb[j];
        }
        __syncthreads();
    }
    float* ob = out + (size_t)b * CC * NPOS;
#pragma unroll
    for (int i = 0; i < 4; ++i) {
        const float4 r = make_float4(acc[i][0], acc[i][1], acc[i][2], acc[i][3]);
        *(float4*)&ob[(size_t)(c0 + trow * 4 + i) * NPOS + j0 + tcol * 4] = r;
    }
}

extern "C" void kernel_launch(void* const* d_in, const int* in_sizes, int n_in,
                              void* d_out, int out_size, void* d_ws, size_t ws_size,
                              hipStream_t stream) {
    const float* fmap    = (const float*)d_in[0];
    const float* gamma   = (const float*)d_in[1];
    const float* w_qk    = (const float*)d_in[2];
    const float* w_v     = (const float*)d_in[3];
    const float* null_kv = (const float*)d_in[4];
    const float* w_out   = (const float*)d_in[5];
    float* out = (float*)d_out;
    float* ws  = (float*)d_ws;
    float* normed = ws;                       // 2*256*2304   = 1,179,648
    float* qkb    = normed + 1179648;         // 2*512*2304   = 2,359,296
    float* vb     = qkb    + 2359296;
    float* inner  = vb     + 2359296;         // 2*2304*512   = 2,359,296
    float* sqbuf  = inner  + 2359296;         // 2*8*2304     = 36,864
    // total 8,294,400 floats ≈ 33.2 MB of workspace

    hipLaunchKernelGGL(k_rmsnorm, dim3(NT, 2),     dim3(256), 0, stream, fmap, gamma, normed);
    hipLaunchKernelGGL(k_proj,    dim3(NT, 16, 2), dim3(256), 0, stream, normed, w_qk, w_v, qkb, vb, sqbuf);
    hipLaunchKernelGGL(k_attn,    dim3(NT, 16),    dim3(256), 0, stream, qkb, vb, null_kv, sqbuf, inner);
    hipLaunchKernelGGL(k_out,     dim3(NT, 4, 2),  dim3(256), 0, stream, w_out, inner, out);
}

// Round 3
// 358.734 us; speedup vs baseline: 1.9540x; 1.7529x over previous
//
#include <hip/hip_runtime.h>
#include <math.h>

#define NPOS 2304   // 48*48
#define CC   256    // DIM
#define DI   512    // HEADS*DIM_HEAD
#define NT   36     // NPOS/64
#define SCALE 0.125f
#define MASKV -100.0f

typedef __attribute__((ext_vector_type(8))) short bf16x8;  // 8 bf16 (4 VGPRs)
typedef __attribute__((ext_vector_type(4))) float f32x4;   // MFMA C/D frag
typedef unsigned short u16;

__device__ inline u16 f2bf(float f) {
    union { float f; unsigned int u; } v; v.f = f;
    return (u16)((v.u + 0x7fffu + ((v.u >> 16) & 1u)) >> 16);
}

// ---------------- Kernel 1: ChannelRMSNorm ----------------
__global__ __launch_bounds__(256) void k_rmsnorm(const float* __restrict__ fmap,
                                                 const float* __restrict__ gamma,
                                                 float* __restrict__ normed) {
    const int b  = blockIdx.y;
    const int j0 = blockIdx.x * 64;
    const int tx = threadIdx.x & 63;
    const int ty = threadIdx.x >> 6;
    __shared__ float red[4][64];
    __shared__ float inv[64];
    __shared__ float gs[256];
    gs[threadIdx.x] = gamma[threadIdx.x];
    const float* fb = fmap + (size_t)b * CC * NPOS;
    float s = 0.0f;
#pragma unroll 8
    for (int i = 0; i < 64; ++i) {
        const int c = ty + 4 * i;
        const float v = fb[c * NPOS + j0 + tx];
        s += v * v;
    }
    red[ty][tx] = s;
    __syncthreads();
    if (threadIdx.x < 64) {
        const float t = red[0][tx] + red[1][tx] + red[2][tx] + red[3][tx];
        inv[tx] = 16.0f / fmaxf(sqrtf(t), 1e-12f);
    }
    __syncthreads();
    float* nb = normed + (size_t)b * CC * NPOS;
#pragma unroll 8
    for (int i = 0; i < 64; ++i) {
        const int c = ty + 4 * i;
        nb[c * NPOS + j0 + tx] = fb[c * NPOS + j0 + tx] * inv[tx] * gs[c];
    }
}

// ---------------- Kernel 2: fused qk/v projection GEMM ----------------
// fp32 accumulate; emits bf16 qkh[b,h,n,64] (row-major per position) for the
// qk half (+ fp32 sq = |q|^2 and ndot = q.null_k), bf16 vt[b,o,n] for v half.
__global__ __launch_bounds__(256) void k_proj(const float* __restrict__ normed,
                                              const float* __restrict__ w_qk,
                                              const float* __restrict__ w_v,
                                              const float* __restrict__ null_kv,
                                              u16* __restrict__ qkh,
                                              u16* __restrict__ vt,
                                              float* __restrict__ sq,
                                              float* __restrict__ ndot) {
    const int b  = blockIdx.z;
    const int o0 = blockIdx.y * 64;   // 0..1023
    const int j0 = blockIdx.x * 64;
    const int t  = threadIdx.x;
    const int trow = t >> 4, tcol = t & 15;
    __shared__ float Ast[16][68];   // Ast[k][o]
    __shared__ float Bs[16][68];    // Bs[k][j]
    __shared__ u16 Tt[64][72];      // bf16 transpose staging [j][d]
    __shared__ float nks[64];
    float acc[4][4] = {};
    const float* W = (o0 < DI) ? w_qk : w_v;
    const int or0 = (o0 < DI) ? o0 : (o0 - DI);
    const int h = or0 >> 6;
    if (o0 < DI && t < 64) nks[t] = null_kv[h * 64 + t];
    const float* nbp = normed + (size_t)b * CC * NPOS;
    for (int k0 = 0; k0 < 256; k0 += 16) {
        {   // A tile: 64 rows x 16 k, transpose into Ast[k][o]
            const int o = t >> 2, kq = t & 3;
            const float4 w4 = *(const float4*)&W[(or0 + o) * 256 + k0 + kq * 4];
            Ast[kq * 4 + 0][o] = w4.x; Ast[kq * 4 + 1][o] = w4.y;
            Ast[kq * 4 + 2][o] = w4.z; Ast[kq * 4 + 3][o] = w4.w;
        }
        {   // B tile: 16 k rows x 64 j
            const int kk = t >> 4, jq = t & 15;
            const float4 b4 = *(const float4*)&nbp[(k0 + kk) * NPOS + j0 + jq * 4];
            *(float4*)&Bs[kk][jq * 4] = b4;
        }
        __syncthreads();
#pragma unroll
        for (int kk = 0; kk < 16; ++kk) {
            const float4 a4 = *(const float4*)&Ast[kk][trow * 4];
            const float4 b4 = *(const float4*)&Bs[kk][tcol * 4];
            const float a[4]  = {a4.x, a4.y, a4.z, a4.w};
            const float bb[4] = {b4.x, b4.y, b4.z, b4.w};
#pragma unroll
            for (int i = 0; i < 4; ++i)
#pragma unroll
                for (int j = 0; j < 4; ++j)
                    acc[i][j] += a[i] * bb[j];
        }
        __syncthreads();
    }
    if (o0 < DI) {
        // sq + ndot partials into Ast/Bs; bf16 transpose into Tt
        float sjj[4], njj[4];
#pragma unroll
        for (int jj = 0; jj < 4; ++jj) {
            float ts = 0.0f, tn = 0.0f;
#pragma unroll
            for (int i = 0; i < 4; ++i) {
                ts += acc[i][jj] * acc[i][jj];
                tn += acc[i][jj] * nks[trow * 4 + i];
            }
            sjj[jj] = ts; njj[jj] = tn;
        }
        *(float4*)&Ast[trow][tcol * 4] = make_float4(sjj[0], sjj[1], sjj[2], sjj[3]);
        *(float4*)&Bs[trow][tcol * 4]  = make_float4(njj[0], njj[1], njj[2], njj[3]);
#pragma unroll
        for (int i = 0; i < 4; ++i)
#pragma unroll
            for (int jj = 0; jj < 4; ++jj)
                Tt[tcol * 4 + jj][trow * 4 + i] = f2bf(acc[i][jj]);
        __syncthreads();
        if (t < 64) {
            float s = 0.0f, n = 0.0f;
#pragma unroll
            for (int r = 0; r < 16; ++r) { s += Ast[r][t]; n += Bs[r][t]; }
            sq  [((size_t)b * 8 + h) * NPOS + j0 + t] = s;
            ndot[((size_t)b * 8 + h) * NPOS + j0 + t] = n;
        }
        const int row = t >> 2, seg = t & 3;
        const int4 w0 = *(const int4*)&Tt[row][seg * 16];
        const int4 w1 = *(const int4*)&Tt[row][seg * 16 + 8];
        u16* dst = qkh + (((size_t)b * 8 + h) * NPOS + j0 + row) * 64 + seg * 16;
        *(int4*)&dst[0] = w0;
        *(int4*)&dst[8] = w1;
    } else {
        u16* dst = vt + (size_t)b * DI * NPOS;
#pragma unroll
        for (int i = 0; i < 4; ++i) {
            const int o = or0 + trow * 4 + i;
            ushort4 r4;
            r4.x = f2bf(acc[i][0]); r4.y = f2bf(acc[i][1]);
            r4.z = f2bf(acc[i][2]); r4.w = f2bf(acc[i][3]);
            *(ushort4*)&dst[(size_t)o * NPOS + j0 + tcol * 4] = r4;
        }
    }
}

// ---------------- Kernel 3: MFMA flash attention (bf16 cross terms) ----------------
// 4 waves/block; wave w handles queries [j0+16w, j0+16w+16). 16x16x32 bf16 MFMA.
// A/B frags loaded directly from global (L1/L2-resident); P round-trips LDS.
__global__ __launch_bounds__(256) void k_attn(const u16* __restrict__ qkh,
                                              const u16* __restrict__ vt,
                                              const float* __restrict__ null_kv,
                                              const float* __restrict__ sq,
                                              const float* __restrict__ ndot,
                                              float* __restrict__ inner) {
    const int qt = blockIdx.x, bh = blockIdx.y;
    const int b = bh >> 3, h = bh & 7;
    const int t = threadIdx.x;
    const int wave = t >> 6, lane = t & 63;
    const int mcol = lane & 15, quad = lane >> 4;
    const int j0 = qt * 64;

    __shared__ u16 Pt[64][68];   // P[query][key] bf16; stride 68 -> 2-way max on C-layout stores

    const u16* qbase = qkh + (size_t)bh * NPOS * 64;
    const u16* vbase = vt + ((size_t)b * DI + h * 64) * NPOS;
    const float* sqb = sq + (size_t)bh * NPOS;
    const float* ndb = ndot + (size_t)bh * NPOS;

    // Q A-frags: row m = lane&15, k-dims quad*8..+7 (two K=32 chunks)
    const bf16x8 aq0 = *(const bf16x8*)&qbase[(j0 + wave * 16 + mcol) * 64 + quad * 8];
    const bf16x8 aq1 = *(const bf16x8*)&qbase[(j0 + wave * 16 + mcol) * 64 + 32 + quad * 8];

    float q2r[4], ndr[4], mreg[4], lreg[4];
    f32x4 oacc[4];
#pragma unroll
    for (int r = 0; r < 4; ++r) {
        const int gq = j0 + wave * 16 + quad * 4 + r;   // C-frag row -> query
        q2r[r] = sqb[gq];
        ndr[r] = ndb[gq];
        mreg[r] = -1e30f; lreg[r] = 0.0f;
    }
#pragma unroll
    for (int nb = 0; nb < 4; ++nb) oacc[nb] = (f32x4){0.f, 0.f, 0.f, 0.f};

    for (int kt = 0; kt < NT; ++kt) {
        const int kj0 = kt * 64;
        // K B-frags (n = key = lane&15 within 16-block, k-dims quad*8..+7)
        bf16x8 bk[4][2];
#pragma unroll
        for (int nb = 0; nb < 4; ++nb) {
            const u16* kr = &qbase[(kj0 + nb * 16 + mcol) * 64 + quad * 8];
            bk[nb][0] = *(const bf16x8*)&kr[0];
            bk[nb][1] = *(const bf16x8*)&kr[32];
        }
        float k2c[4];
#pragma unroll
        for (int nb = 0; nb < 4; ++nb) k2c[nb] = sqb[kj0 + nb * 16 + mcol];

        // S = Q.K^T  (fp32 accum)
        f32x4 c[4];
#pragma unroll
        for (int nb = 0; nb < 4; ++nb) {
            c[nb] = (f32x4){0.f, 0.f, 0.f, 0.f};
            c[nb] = __builtin_amdgcn_mfma_f32_16x16x32_bf16(aq0, bk[nb][0], c[nb], 0, 0, 0);
            c[nb] = __builtin_amdgcn_mfma_f32_16x16x32_bf16(aq1, bk[nb][1], c[nb], 0, 0, 0);
        }

        // sim + self-mask + online softmax on C-frags
        float tm[4] = {-1e30f, -1e30f, -1e30f, -1e30f};
#pragma unroll
        for (int nb = 0; nb < 4; ++nb) {
            const int gk = kj0 + nb * 16 + mcol;
#pragma unroll
            for (int r = 0; r < 4; ++r) {
                const int gq = j0 + wave * 16 + quad * 4 + r;
                const float d2 = fmaxf(q2r[r] + k2c[nb] - 2.0f * c[nb][r], 0.0f);
                float s = -sqrtf(d2) * SCALE;
                if (gq == gk) s = MASKV;
                c[nb][r] = s;
                tm[r] = fmaxf(tm[r], s);
            }
        }
#pragma unroll
        for (int mk = 1; mk <= 8; mk <<= 1)
#pragma unroll
            for (int r = 0; r < 4; ++r) tm[r] = fmaxf(tm[r], __shfl_xor(tm[r], mk));
        float alpha[4], rs[4] = {0.f, 0.f, 0.f, 0.f};
#pragma unroll
        for (int r = 0; r < 4; ++r) {
            const float mnew = fmaxf(mreg[r], tm[r]);
            alpha[r] = __expf(mreg[r] - mnew);
            mreg[r] = mnew;
        }
#pragma unroll
        for (int nb = 0; nb < 4; ++nb)
#pragma unroll
            for (int r = 0; r < 4; ++r) {
                const float e = __expf(c[nb][r] - mreg[r]);
                rs[r] += e;
                Pt[wave * 16 + quad * 4 + r][nb * 16 + mcol] = f2bf(e);
            }
#pragma unroll
        for (int mk = 1; mk <= 8; mk <<= 1)
#pragma unroll
            for (int r = 0; r < 4; ++r) rs[r] += __shfl_xor(rs[r], mk);
#pragma unroll
        for (int r = 0; r < 4; ++r) lreg[r] = lreg[r] * alpha[r] + rs[r];
#pragma unroll
        for (int nb = 0; nb < 4; ++nb)
#pragma unroll
            for (int r = 0; r < 4; ++r) oacc[nb][r] *= alpha[r];
        __syncthreads();   // Pt stores visible

        // P A-frags: row = wave*16 + (lane&15), keys kc*32+quad*8..+7 (b64 pairs)
        bf16x8 ap0, ap1;
        {
            const int prow = wave * 16 + mcol;
            const short4 a0 = *(const short4*)&Pt[prow][quad * 8];
            const short4 a1 = *(const short4*)&Pt[prow][quad * 8 + 4];
            const short4 a2 = *(const short4*)&Pt[prow][32 + quad * 8];
            const short4 a3 = *(const short4*)&Pt[prow][32 + quad * 8 + 4];
            ap0 = (bf16x8){a0.x, a0.y, a0.z, a0.w, a1.x, a1.y, a1.z, a1.w};
            ap1 = (bf16x8){a2.x, a2.y, a2.z, a2.w, a3.x, a3.y, a3.z, a3.w};
        }
        __syncthreads();   // all reads drained before next-iter stores

        // PV: O[q][dim] += P.V ; B-frag n = dim, contraction = key (vt is [dim][key])
#pragma unroll
        for (int nb = 0; nb < 4; ++nb) {
            const u16* vr = &vbase[(size_t)(nb * 16 + mcol) * NPOS + kj0 + quad * 8];
            const bf16x8 bv0 = *(const bf16x8*)&vr[0];
            const bf16x8 bv1 = *(const bf16x8*)&vr[32];
            oacc[nb] = __builtin_amdgcn_mfma_f32_16x16x32_bf16(ap0, bv0, oacc[nb], 0, 0, 0);
            oacc[nb] = __builtin_amdgcn_mfma_f32_16x16x32_bf16(ap1, bv1, oacc[nb], 0, 0, 0);
        }
    }

    // null key/value epilogue (exact fp32 via precomputed ndot)
    float nk2 = 0.0f;
#pragma unroll 8
    for (int d = 0; d < 64; ++d) { const float nk = null_kv[h * 64 + d]; nk2 += nk * nk; }
    float nv[4];
#pragma unroll
    for (int nb = 0; nb < 4; ++nb) nv[nb] = null_kv[DI + h * 64 + nb * 16 + mcol];
    float* ob = inner + (size_t)b * NPOS * DI;
#pragma unroll
    for (int r = 0; r < 4; ++r) {
        const float d2 = fmaxf(q2r[r] + nk2 - 2.0f * ndr[r], 0.0f);
        const float simn = -sqrtf(d2) * SCALE;
        const float mnew = fmaxf(mreg[r], simn);
        const float alpha = __expf(mreg[r] - mnew);
        const float beta  = __expf(simn - mnew);
        const float l = lreg[r] * alpha + beta;
        const float il = 1.0f / l;
        const int row = j0 + wave * 16 + quad * 4 + r;
#pragma unroll
        for (int nb = 0; nb < 4; ++nb)
            ob[(size_t)row * DI + h * 64 + nb * 16 + mcol] =
                (oacc[nb][r] * alpha + beta * nv[nb]) * il;
    }
}

// ---------------- Kernel 4: output projection ----------------
__global__ __launch_bounds__(256) void k_out(const float* __restrict__ w_out,
                                             const float* __restrict__ inner,
                                             float* __restrict__ out) {
    const int b  = blockIdx.z;
    const int c0 = blockIdx.y * 64;
    const int j0 = blockIdx.x * 64;
    const int t  = threadIdx.x;
    const int trow = t >> 4, tcol = t & 15;
    __shared__ float Ast[16][68];  // Ast[k][c]
    __shared__ float Bst[16][68];  // Bst[k][j]
    float acc[4][4] = {};
    const float* ib = inner + (size_t)b * NPOS * DI;
    for (int k0 = 0; k0 < 512; k0 += 16) {
        {
            const int cr = t >> 2, kq = t & 3;
            const float4 w4 = *(const float4*)&w_out[(c0 + cr) * DI + k0 + kq * 4];
            Ast[kq * 4 + 0][cr] = w4.x; Ast[kq * 4 + 1][cr] = w4.y;
            Ast[kq * 4 + 2][cr] = w4.z; Ast[kq * 4 + 3][cr] = w4.w;
        }
        {
            const int jr = t >> 2, kq = t & 3;
            const float4 i4 = *(const float4*)&ib[(size_t)(j0 + jr) * DI + k0 + kq * 4];
            Bst[kq * 4 + 0][jr] = i4.x; Bst[kq * 4 + 1][jr] = i4.y;
            Bst[kq * 4 + 2][jr] = i4.z; Bst[kq * 4 + 3][jr] = i4.w;
        }
        __syncthreads();
#pragma unroll
        for (int kk = 0; kk < 16; ++kk) {
            const float4 a4 = *(const float4*)&Ast[kk][trow * 4];
            const float4 b4 = *(const float4*)&Bst[kk][tcol * 4];
            const float a[4]  = {a4.x, a4.y, a4.z, a4.w};
            const float bb[4] = {b4.x, b4.y, b4.z, b4.w};
#pragma unroll
            for (int i = 0; i < 4; ++i)
#pragma unroll
                for (int j = 0; j < 4; ++j)
                    acc[i][j] += a[i] * bb[j];
        }
        __syncthreads();
    }
    float* ob = out + (size_t)b * CC * NPOS;
#pragma unroll
    for (int i = 0; i < 4; ++i) {
        const float4 r = make_float4(acc[i][0], acc[i][1], acc[i][2], acc[i][3]);
        *(float4*)&ob[(size_t)(c0 + trow * 4 + i) * NPOS + j0 + tcol * 4] = r;
    }
}

extern "C" void kernel_launch(void* const* d_in, const int* in_sizes, int n_in,
                              void* d_out, int out_size, void* d_ws, size_t ws_size,
                              hipStream_t stream) {
    const float* fmap    = (const float*)d_in[0];
    const float* gamma   = (const float*)d_in[1];
    const float* w_qk    = (const float*)d_in[2];
    const float* w_v     = (const float*)d_in[3];
    const float* null_kv = (const float*)d_in[4];
    const float* w_out   = (const float*)d_in[5];
    float* out = (float*)d_out;
    float* ws  = (float*)d_ws;
    float* normed = ws;                                  // 2*256*2304 fp32 = 1,179,648 fl
    u16*   qkh    = (u16*)(normed + 1179648);            // 2*8*2304*64 bf16 = 2,359,296 u16
    u16*   vtb    = qkh + 2359296;                       // 2*512*2304 bf16  = 2,359,296 u16
    float* inner  = (float*)(vtb + 2359296);             // 2*2304*512 fp32  = 2,359,296 fl
    float* sqbuf  = inner + 2359296;                     // 2*8*2304
    float* ndbuf  = sqbuf + 36864;                       // 2*8*2304
    // total ~ 24 MB

    hipLaunchKernelGGL(k_rmsnorm, dim3(NT, 2),     dim3(256), 0, stream, fmap, gamma, normed);
    hipLaunchKernelGGL(k_proj,    dim3(NT, 16, 2), dim3(256), 0, stream, normed, w_qk, w_v, null_kv, qkh, vtb, sqbuf, ndbuf);
    hipLaunchKernelGGL(k_attn,    dim3(NT, 16),    dim3(256), 0, stream, qkh, vtb, null_kv, sqbuf, ndbuf, inner);
    hipLaunchKernelGGL(k_out,     dim3(NT, 4, 2),  dim3(256), 0, stream, w_out, inner, out);
}

// Round 4
// 299.375 us; speedup vs baseline: 2.3414x; 1.1983x over previous
//
#include <hip/hip_runtime.h>
#include <math.h>

#define NPOS 2304   // 48*48
#define CC   256    // DIM
#define DI   512    // HEADS*DIM_HEAD
#define NT   36     // NPOS/64
#define SCALE 0.125f
#define MASKV -100.0f
// exp(-SCALE*sqrt(d2)) = exp2(-SCALE*log2(e)*sqrt(d2))
#define NEGSL2E (-0.18033688011112042f)

typedef __attribute__((ext_vector_type(8))) short bf16x8;  // 8 bf16 (4 VGPRs)
typedef __attribute__((ext_vector_type(4))) float f32x4;   // MFMA C/D frag
typedef unsigned short u16;
typedef unsigned int u32;

__device__ inline u16 f2bf(float f) {
    union { float f; unsigned int u; } v; v.f = f;
    return (u16)((v.u + 0x7fffu + ((v.u >> 16) & 1u)) >> 16);
}

// ---------------- Kernel 1: ChannelRMSNorm ----------------
__global__ __launch_bounds__(256) void k_rmsnorm(const float* __restrict__ fmap,
                                                 const float* __restrict__ gamma,
                                                 float* __restrict__ normed) {
    const int b  = blockIdx.y;
    const int j0 = blockIdx.x * 64;
    const int tx = threadIdx.x & 63;
    const int ty = threadIdx.x >> 6;
    __shared__ float red[4][64];
    __shared__ float inv[64];
    __shared__ float gs[256];
    gs[threadIdx.x] = gamma[threadIdx.x];
    const float* fb = fmap + (size_t)b * CC * NPOS;
    float s = 0.0f;
#pragma unroll 8
    for (int i = 0; i < 64; ++i) {
        const int c = ty + 4 * i;
        const float v = fb[c * NPOS + j0 + tx];
        s += v * v;
    }
    red[ty][tx] = s;
    __syncthreads();
    if (threadIdx.x < 64) {
        const float t = red[0][tx] + red[1][tx] + red[2][tx] + red[3][tx];
        inv[tx] = 16.0f / fmaxf(sqrtf(t), 1e-12f);
    }
    __syncthreads();
    float* nb = normed + (size_t)b * CC * NPOS;
#pragma unroll 8
    for (int i = 0; i < 64; ++i) {
        const int c = ty + 4 * i;
        nb[c * NPOS + j0 + tx] = fb[c * NPOS + j0 + tx] * inv[tx] * gs[c];
    }
}

// ---------------- Kernel 2: fused qk/v projection GEMM ----------------
// fp32 accumulate; emits bf16 qkh[b,h,n,64] + fp32 sq/ndot, bf16 vt[b,o,n].
__global__ __launch_bounds__(256) void k_proj(const float* __restrict__ normed,
                                              const float* __restrict__ w_qk,
                                              const float* __restrict__ w_v,
                                              const float* __restrict__ null_kv,
                                              u16* __restrict__ qkh,
                                              u16* __restrict__ vt,
                                              float* __restrict__ sq,
                                              float* __restrict__ ndot) {
    const int b  = blockIdx.z;
    const int o0 = blockIdx.y * 64;   // 0..1023
    const int j0 = blockIdx.x * 64;
    const int t  = threadIdx.x;
    const int trow = t >> 4, tcol = t & 15;
    __shared__ float Ast[16][68];   // Ast[k][o]
    __shared__ float Bs[16][68];    // Bs[k][j]
    __shared__ u16 Tt[64][72];      // bf16 transpose staging [j][d]
    __shared__ float nks[64];
    float acc[4][4] = {};
    const float* W = (o0 < DI) ? w_qk : w_v;
    const int or0 = (o0 < DI) ? o0 : (o0 - DI);
    const int h = or0 >> 6;
    if (o0 < DI && t < 64) nks[t] = null_kv[h * 64 + t];
    const float* nbp = normed + (size_t)b * CC * NPOS;
    for (int k0 = 0; k0 < 256; k0 += 16) {
        {
            const int o = t >> 2, kq = t & 3;
            const float4 w4 = *(const float4*)&W[(or0 + o) * 256 + k0 + kq * 4];
            Ast[kq * 4 + 0][o] = w4.x; Ast[kq * 4 + 1][o] = w4.y;
            Ast[kq * 4 + 2][o] = w4.z; Ast[kq * 4 + 3][o] = w4.w;
        }
        {
            const int kk = t >> 4, jq = t & 15;
            const float4 b4 = *(const float4*)&nbp[(k0 + kk) * NPOS + j0 + jq * 4];
            *(float4*)&Bs[kk][jq * 4] = b4;
        }
        __syncthreads();
#pragma unroll
        for (int kk = 0; kk < 16; ++kk) {
            const float4 a4 = *(const float4*)&Ast[kk][trow * 4];
            const float4 b4 = *(const float4*)&Bs[kk][tcol * 4];
            const float a[4]  = {a4.x, a4.y, a4.z, a4.w};
            const float bb[4] = {b4.x, b4.y, b4.z, b4.w};
#pragma unroll
            for (int i = 0; i < 4; ++i)
#pragma unroll
                for (int j = 0; j < 4; ++j)
                    acc[i][j] += a[i] * bb[j];
        }
        __syncthreads();
    }
    if (o0 < DI) {
        float sjj[4], njj[4];
#pragma unroll
        for (int jj = 0; jj < 4; ++jj) {
            float ts = 0.0f, tn = 0.0f;
#pragma unroll
            for (int i = 0; i < 4; ++i) {
                ts += acc[i][jj] * acc[i][jj];
                tn += acc[i][jj] * nks[trow * 4 + i];
            }
            sjj[jj] = ts; njj[jj] = tn;
        }
        *(float4*)&Ast[trow][tcol * 4] = make_float4(sjj[0], sjj[1], sjj[2], sjj[3]);
        *(float4*)&Bs[trow][tcol * 4]  = make_float4(njj[0], njj[1], njj[2], njj[3]);
#pragma unroll
        for (int i = 0; i < 4; ++i)
#pragma unroll
            for (int jj = 0; jj < 4; ++jj)
                Tt[tcol * 4 + jj][trow * 4 + i] = f2bf(acc[i][jj]);
        __syncthreads();
        if (t < 64) {
            float s = 0.0f, n = 0.0f;
#pragma unroll
            for (int r = 0; r < 16; ++r) { s += Ast[r][t]; n += Bs[r][t]; }
            sq  [((size_t)b * 8 + h) * NPOS + j0 + t] = s;
            ndot[((size_t)b * 8 + h) * NPOS + j0 + t] = n;
        }
        const int row = t >> 2, seg = t & 3;
        const int4 w0 = *(const int4*)&Tt[row][seg * 16];
        const int4 w1 = *(const int4*)&Tt[row][seg * 16 + 8];
        u16* dst = qkh + (((size_t)b * 8 + h) * NPOS + j0 + row) * 64 + seg * 16;
        *(int4*)&dst[0] = w0;
        *(int4*)&dst[8] = w1;
    } else {
        u16* dst = vt + (size_t)b * DI * NPOS;
#pragma unroll
        for (int i = 0; i < 4; ++i) {
            const int o = or0 + trow * 4 + i;
            ushort4 r4;
            r4.x = f2bf(acc[i][0]); r4.y = f2bf(acc[i][1]);
            r4.z = f2bf(acc[i][2]); r4.w = f2bf(acc[i][3]);
            *(ushort4*)&dst[(size_t)o * NPOS + j0 + tcol * 4] = r4;
        }
    }
}

// ---------------- Kernel 3: barrier-free MFMA flash attention ----------------
// One wave per block, 16 queries per wave. S^T = K.Q^T and O^T = V^T.P^T so the
// P slice is wave-private (no __syncthreads). m=0 fixed softmax (sim <= 0 always);
// denominator accumulated by MFMA from the SAME truncated bf16 P as the numerator.
__global__ __launch_bounds__(64, 3) void k_attn(const u16* __restrict__ qkh,
                                                const u16* __restrict__ vt,
                                                const float* __restrict__ null_kv,
                                                const float* __restrict__ sq,
                                                const float* __restrict__ ndot,
                                                float* __restrict__ inner) {
    const int q16 = blockIdx.x * 16;            // 144 query tiles of 16
    const int bh = blockIdx.y;
    const int b = bh >> 3, h = bh & 7;
    const int lane = threadIdx.x;               // 0..63
    const int mcol = lane & 15, quad = lane >> 4;

    __shared__ u16 Pt[16][72];   // wave-private P[query][key] bf16 (pad 72: rows 16B-aligned, 2-way banks)

    const u16* qbase = qkh + (size_t)bh * NPOS * 64;
    const u16* vbase = vt + ((size_t)b * DI + h * 64) * NPOS;
    const float* sqb = sq + (size_t)bh * NPOS;

    // Q B-frags: n = query = mcol, contraction = d (two K=32 chunks)
    const bf16x8 bq0 = *(const bf16x8*)&qbase[(q16 + mcol) * 64 + quad * 8];
    const bf16x8 bq1 = *(const bf16x8*)&qbase[(q16 + mcol) * 64 + 32 + quad * 8];
    const float q2 = sqb[q16 + mcol];           // per-lane query |q|^2

    const bf16x8 ones = {0x3F80, 0x3F80, 0x3F80, 0x3F80, 0x3F80, 0x3F80, 0x3F80, 0x3F80};
    const int ktm = q16 >> 6, nbm = (q16 >> 4) & 3;

    f32x4 oacc[4];
#pragma unroll
    for (int nb = 0; nb < 4; ++nb) oacc[nb] = (f32x4){0.f, 0.f, 0.f, 0.f};
    f32x4 lsum = (f32x4){0.f, 0.f, 0.f, 0.f};

    // K A-frag double buffer; prefetch tile 0
    bf16x8 bk[2][4][2];
#pragma unroll
    for (int nb = 0; nb < 4; ++nb) {
        const u16* kr = &qbase[(nb * 16 + mcol) * 64 + quad * 8];
        bk[0][nb][0] = *(const bf16x8*)&kr[0];
        bk[0][nb][1] = *(const bf16x8*)&kr[32];
    }

#pragma unroll 2
    for (int kt = 0; kt < NT; ++kt) {
        const int cur = kt & 1;
        const int kj0 = kt * 64;

        // k2 per (nb, r): key = kj0 + nb*16 + quad*4 + r
        float4 k2q[4];
#pragma unroll
        for (int nb = 0; nb < 4; ++nb)
            k2q[nb] = *(const float4*)&sqb[kj0 + nb * 16 + quad * 4];

        // S^T = K.Q^T
        f32x4 c[4];
#pragma unroll
        for (int nb = 0; nb < 4; ++nb) {
            c[nb] = (f32x4){0.f, 0.f, 0.f, 0.f};
            c[nb] = __builtin_amdgcn_mfma_f32_16x16x32_bf16(bk[cur][nb][0], bq0, c[nb], 0, 0, 0);
            c[nb] = __builtin_amdgcn_mfma_f32_16x16x32_bf16(bk[cur][nb][1], bq1, c[nb], 0, 0, 0);
        }

        // prefetch next K tile
        const int kjn = (kt + 1 < NT) ? kj0 + 64 : 0;
#pragma unroll
        for (int nb = 0; nb < 4; ++nb) {
            const u16* kr = &qbase[(kjn + nb * 16 + mcol) * 64 + quad * 8];
            bk[cur ^ 1][nb][0] = *(const bf16x8*)&kr[0];
            bk[cur ^ 1][nb][1] = *(const bf16x8*)&kr[32];
        }
        // V A-frags for this tile (independent of softmax -> issued early)
        bf16x8 bv[4][2];
#pragma unroll
        for (int nb = 0; nb < 4; ++nb) {
            const u16* vr = &vbase[(size_t)(nb * 16 + mcol) * NPOS + kj0 + quad * 8];
            bv[nb][0] = *(const bf16x8*)&vr[0];
            bv[nb][1] = *(const bf16x8*)&vr[32];
        }

        // softmax numerator: e = exp2(-c1*sqrt(max(q2+k2-2*qk, 0))), m = 0 fixed
#pragma unroll
        for (int nb = 0; nb < 4; ++nb) {
            float e[4];
#pragma unroll
            for (int r = 0; r < 4; ++r) {
                const float pre = q2 + ((const float*)&k2q[nb])[r];
                const float d2 = fmaxf(__builtin_fmaf(c[nb][r], -2.0f, pre), 0.0f);
                e[r] = __builtin_amdgcn_exp2f(NEGSL2E * __builtin_amdgcn_sqrtf(d2));
            }
            if (kt == ktm && nb == nbm) {
                // self key: key_in_block = quad*4+r == mcol  -> exp(MASKV) ~ 0
#pragma unroll
                for (int r = 0; r < 4; ++r)
                    if (quad * 4 + r == mcol) e[r] = 0.0f;
            }
            // truncate-pack two floats -> u32 of two bf16 (hi16), write 8B
            const u32 p01 = __builtin_amdgcn_perm(__float_as_uint(e[1]), __float_as_uint(e[0]), 0x07060302u);
            const u32 p23 = __builtin_amdgcn_perm(__float_as_uint(e[3]), __float_as_uint(e[2]), 0x07060302u);
            *(uint2*)&Pt[mcol][nb * 16 + quad * 4] = make_uint2(p01, p23);
        }

        // P^T B-frags (wave-private: compiler inserts lgkmcnt, no barrier)
        const bf16x8 bp0 = *(const bf16x8*)&Pt[mcol][quad * 8];
        const bf16x8 bp1 = *(const bf16x8*)&Pt[mcol][32 + quad * 8];

        // O^T += V^T.P^T ; denominator from the same truncated P
#pragma unroll
        for (int nb = 0; nb < 4; ++nb) {
            oacc[nb] = __builtin_amdgcn_mfma_f32_16x16x32_bf16(bv[nb][0], bp0, oacc[nb], 0, 0, 0);
            oacc[nb] = __builtin_amdgcn_mfma_f32_16x16x32_bf16(bv[nb][1], bp1, oacc[nb], 0, 0, 0);
        }
        lsum = __builtin_amdgcn_mfma_f32_16x16x32_bf16(ones, bp0, lsum, 0, 0, 0);
        lsum = __builtin_amdgcn_mfma_f32_16x16x32_bf16(ones, bp1, lsum, 0, 0, 0);
    }

    // null key/value epilogue (m=0: beta = exp(sim_null))
    float nk2 = 0.0f;
#pragma unroll 8
    for (int d = 0; d < 64; ++d) { const float nk = null_kv[h * 64 + d]; nk2 += nk * nk; }
    const float nd = ndot[(size_t)bh * NPOS + q16 + mcol];
    const float d2n = fmaxf(q2 + nk2 - 2.0f * nd, 0.0f);
    const float beta = __expf(-sqrtf(d2n) * SCALE);
    const float il = 1.0f / (lsum[0] + beta);

    float* ob = inner + ((size_t)b * NPOS + q16 + mcol) * DI + h * 64;
#pragma unroll
    for (int nb = 0; nb < 4; ++nb) {
        const float4 nv4 = *(const float4*)&null_kv[DI + h * 64 + nb * 16 + quad * 4];
        float4 r;
        r.x = (oacc[nb][0] + beta * nv4.x) * il;
        r.y = (oacc[nb][1] + beta * nv4.y) * il;
        r.z = (oacc[nb][2] + beta * nv4.z) * il;
        r.w = (oacc[nb][3] + beta * nv4.w) * il;
        *(float4*)&ob[nb * 16 + quad * 4] = r;
    }
}

// ---------------- Kernel 4: output projection ----------------
__global__ __launch_bounds__(256) void k_out(const float* __restrict__ w_out,
                                             const float* __restrict__ inner,
                                             float* __restrict__ out) {
    const int b  = blockIdx.z;
    const int c0 = blockIdx.y * 64;
    const int j0 = blockIdx.x * 64;
    const int t  = threadIdx.x;
    const int trow = t >> 4, tcol = t & 15;
    __shared__ float Ast[16][68];  // Ast[k][c]
    __shared__ float Bst[16][68];  // Bst[k][j]
    float acc[4][4] = {};
    const float* ib = inner + (size_t)b * NPOS * DI;
    for (int k0 = 0; k0 < 512; k0 += 16) {
        {
            const int cr = t >> 2, kq = t & 3;
            const float4 w4 = *(const float4*)&w_out[(c0 + cr) * DI + k0 + kq * 4];
            Ast[kq * 4 + 0][cr] = w4.x; Ast[kq * 4 + 1][cr] = w4.y;
            Ast[kq * 4 + 2][cr] = w4.z; Ast[kq * 4 + 3][cr] = w4.w;
        }
        {
            const int jr = t >> 2, kq = t & 3;
            const float4 i4 = *(const float4*)&ib[(size_t)(j0 + jr) * DI + k0 + kq * 4];
            Bst[kq * 4 + 0][jr] = i4.x; Bst[kq * 4 + 1][jr] = i4.y;
            Bst[kq * 4 + 2][jr] = i4.z; Bst[kq * 4 + 3][jr] = i4.w;
        }
        __syncthreads();
#pragma unroll
        for (int kk = 0; kk < 16; ++kk) {
            const float4 a4 = *(const float4*)&Ast[kk][trow * 4];
            const float4 b4 = *(const float4*)&Bst[kk][tcol * 4];
            const float a[4]  = {a4.x, a4.y, a4.z, a4.w};
            const float bb[4] = {b4.x, b4.y, b4.z, b4.w};
#pragma unroll
            for (int i = 0; i < 4; ++i)
#pragma unroll
                for (int j = 0; j < 4; ++j)
                    acc[i][j] += a[i] * bb[j];
        }
        __syncthreads();
    }
    float* ob = out + (size_t)b * CC * NPOS;
#pragma unroll
    for (int i = 0; i < 4; ++i) {
        const float4 r = make_float4(acc[i][0], acc[i][1], acc[i][2], acc[i][3]);
        *(float4*)&ob[(size_t)(c0 + trow * 4 + i) * NPOS + j0 + tcol * 4] = r;
    }
}

extern "C" void kernel_launch(void* const* d_in, const int* in_sizes, int n_in,
                              void* d_out, int out_size, void* d_ws, size_t ws_size,
                              hipStream_t stream) {
    const float* fmap    = (const float*)d_in[0];
    const float* gamma   = (const float*)d_in[1];
    const float* w_qk    = (const float*)d_in[2];
    const float* w_v     = (const float*)d_in[3];
    const float* null_kv = (const float*)d_in[4];
    const float* w_out   = (const float*)d_in[5];
    float* out = (float*)d_out;
    float* ws  = (float*)d_ws;
    float* normed = ws;                                  // 2*256*2304 fp32
    u16*   qkh    = (u16*)(normed + 1179648);            // 2*8*2304*64 bf16
    u16*   vtb    = qkh + 2359296;                       // 2*512*2304 bf16
    float* inner  = (float*)(vtb + 2359296);             // 2*2304*512 fp32
    float* sqbuf  = inner + 2359296;                     // 2*8*2304
    float* ndbuf  = sqbuf + 36864;                       // 2*8*2304
    // total ~ 24 MB

    hipLaunchKernelGGL(k_rmsnorm, dim3(NT, 2),      dim3(256), 0, stream, fmap, gamma, normed);
    hipLaunchKernelGGL(k_proj,    dim3(NT, 16, 2),  dim3(256), 0, stream, normed, w_qk, w_v, null_kv, qkh, vtb, sqbuf, ndbuf);
    hipLaunchKernelGGL(k_attn,    dim3(144, 16),    dim3(64),  0, stream, qkh, vtb, null_kv, sqbuf, ndbuf, inner);
    hipLaunchKernelGGL(k_out,     dim3(NT, 4, 2),   dim3(256), 0, stream, w_out, inner, out);
}